// Round 1
// baseline (825.548 us; speedup 1.0000x reference)
//
#include <hip/hip_runtime.h>
#include <hip/hip_bf16.h>

#define T_TOKENS 8192
#define H_DIM    1024
#define N_EXP    8

#define BM 128
#define BN 128
#define BK 64

typedef __attribute__((ext_vector_type(8))) __bf16 bf16x8;
typedef __attribute__((ext_vector_type(4))) float  f32x4;

__device__ __forceinline__ unsigned short f2bf(float f) {
  unsigned u = __float_as_uint(f);
  u += 0x7fff + ((u >> 16) & 1);   // round-to-nearest-even
  return (unsigned short)(u >> 16);
}

// ---------------- Router: one wave per token ----------------
__global__ __launch_bounds__(256) void router_kernel(
    const float* __restrict__ x, const float* __restrict__ gw,
    const float* __restrict__ gb, float* __restrict__ logits_out,
    int* __restrict__ cnt, int* __restrict__ lst, float* __restrict__ wpair)
{
  const int tid = threadIdx.x;
  const int lane = tid & 63;
  const int w = tid >> 6;
  const int t = blockIdx.x * 4 + w;
  const float* xr = x + (size_t)t * H_DIM;

  float acc[8];
  #pragma unroll
  for (int e = 0; e < 8; ++e) acc[e] = 0.f;

  #pragma unroll
  for (int i = 0; i < H_DIM / 64; ++i) {
    const int h = i * 64 + lane;
    const float xv = xr[h];
    const float4 g0 = *(const float4*)&gw[h * 8 + 0];
    const float4 g1 = *(const float4*)&gw[h * 8 + 4];
    acc[0] += xv * g0.x; acc[1] += xv * g0.y;
    acc[2] += xv * g0.z; acc[3] += xv * g0.w;
    acc[4] += xv * g1.x; acc[5] += xv * g1.y;
    acc[6] += xv * g1.z; acc[7] += xv * g1.w;
  }
  #pragma unroll
  for (int off = 32; off; off >>= 1) {
    #pragma unroll
    for (int e = 0; e < 8; ++e) acc[e] += __shfl_xor(acc[e], off);
  }
  if (lane == 0) {
    float lg[8];
    #pragma unroll
    for (int e = 0; e < 8; ++e) lg[e] = acc[e] + gb[e];
    #pragma unroll
    for (int e = 0; e < 8; ++e) logits_out[(size_t)t * N_EXP + e] = lg[e];
    // top-2, first-occurrence on ties (matches jax.lax.top_k)
    int e0 = 0; float v0 = lg[0];
    #pragma unroll
    for (int e = 1; e < 8; ++e) { if (lg[e] > v0) { v0 = lg[e]; e0 = e; } }
    int e1 = -1; float v1 = -3.4e38f;
    #pragma unroll
    for (int e = 0; e < 8; ++e) { if (e != e0 && lg[e] > v1) { v1 = lg[e]; e1 = e; } }
    const float ew = expf(v1 - v0);
    const float r0 = 1.f / (1.f + ew);
    const float r1 = ew / (1.f + ew);
    wpair[2 * t + 0] = r0;
    wpair[2 * t + 1] = r1;
    int p0 = atomicAdd(&cnt[e0], 1); lst[e0 * T_TOKENS + p0] = 2 * t + 0;
    int p1 = atomicAdd(&cnt[e1], 1); lst[e1 * T_TOKENS + p1] = 2 * t + 1;
  }
}

// ---------------- GEMM1: h1[pair] = relu(x_gather @ W1[e] + b1[e]) ----------------
__global__ __launch_bounds__(256, 2) void gemm1_kernel(
    const float* __restrict__ x, const float* __restrict__ w1,
    const float* __restrict__ b1, const int* __restrict__ cnt,
    const int* __restrict__ lst, unsigned short* __restrict__ h1)
{
  const int e = blockIdx.z;
  const int c = cnt[e];
  const int m0 = blockIdx.y * BM;
  if (m0 >= c) return;
  const int n0 = blockIdx.x * BN;
  const float* W = w1 + (size_t)e * H_DIM * H_DIM;
  const int* le = lst + e * T_TOKENS;

  __shared__ unsigned short As[BM * BK];
  __shared__ unsigned short Bs[BN * BK];

  const int tid = threadIdx.x;
  const int lane = tid & 63;
  const int wid = tid >> 6;
  const int wr = (wid >> 1) * 64;
  const int wc = (wid & 1) * 64;
  const int lr = lane & 15;
  const int kh = (lane >> 4) << 3;
  const int sw = (lane & 7) << 3;

  // A staging precompute: 8 float4 per thread
  const float* aptr[8];
  int adst[8];
  #pragma unroll
  for (int i = 0; i < 8; ++i) {
    const int idx = i * 256 + tid;
    const int m = idx >> 4;
    const int k4 = (idx & 15) << 2;
    const int gm = m0 + m;
    const int pair = (gm < c) ? le[gm] : le[0];
    aptr[i] = x + (size_t)(pair >> 1) * H_DIM + k4;
    adst[i] = m * BK + (k4 ^ ((m & 7) << 3));
  }
  // B staging precompute: 8 float4 per thread (read along n, scatter-transpose)
  const float* bptr[8];
  int bn4[8], bkr[8];
  #pragma unroll
  for (int i = 0; i < 8; ++i) {
    const int idx = i * 256 + tid;
    const int kr = idx >> 5;
    const int n4 = (idx & 31) << 2;
    bptr[i] = W + (size_t)kr * H_DIM + n0 + n4;
    bn4[i] = n4; bkr[i] = kr;
  }

  f32x4 acc[4][4];
  #pragma unroll
  for (int i = 0; i < 4; ++i)
    #pragma unroll
    for (int j = 0; j < 4; ++j) acc[i][j] = (f32x4){0.f, 0.f, 0.f, 0.f};

  for (int kt = 0; kt < H_DIM; kt += BK) {
    __syncthreads();
    #pragma unroll
    for (int i = 0; i < 8; ++i) {
      const float4 v = *(const float4*)(aptr[i] + kt);
      short4 s4;
      ((unsigned short*)&s4)[0] = f2bf(v.x);
      ((unsigned short*)&s4)[1] = f2bf(v.y);
      ((unsigned short*)&s4)[2] = f2bf(v.z);
      ((unsigned short*)&s4)[3] = f2bf(v.w);
      *(short4*)&As[adst[i]] = s4;
    }
    #pragma unroll
    for (int i = 0; i < 8; ++i) {
      const float4 v = *(const float4*)(bptr[i] + (size_t)kt * H_DIM);
      const int n4 = bn4[i], kr = bkr[i];
      Bs[(n4 + 0) * BK + (kr ^ (((n4 + 0) & 7) << 3))] = f2bf(v.x);
      Bs[(n4 + 1) * BK + (kr ^ (((n4 + 1) & 7) << 3))] = f2bf(v.y);
      Bs[(n4 + 2) * BK + (kr ^ (((n4 + 2) & 7) << 3))] = f2bf(v.z);
      Bs[(n4 + 3) * BK + (kr ^ (((n4 + 3) & 7) << 3))] = f2bf(v.w);
    }
    __syncthreads();
    #pragma unroll
    for (int kk = 0; kk < BK; kk += 32) {
      bf16x8 a[4], b[4];
      #pragma unroll
      for (int mi = 0; mi < 4; ++mi) {
        const int row = wr + mi * 16 + lr;
        a[mi] = *reinterpret_cast<const bf16x8*>(&As[row * BK + ((kk + kh) ^ sw)]);
      }
      #pragma unroll
      for (int ni = 0; ni < 4; ++ni) {
        const int row = wc + ni * 16 + lr;
        b[ni] = *reinterpret_cast<const bf16x8*>(&Bs[row * BK + ((kk + kh) ^ sw)]);
      }
      #pragma unroll
      for (int mi = 0; mi < 4; ++mi)
        #pragma unroll
        for (int ni = 0; ni < 4; ++ni)
          acc[mi][ni] = __builtin_amdgcn_mfma_f32_16x16x32_bf16(a[mi], b[ni], acc[mi][ni], 0, 0, 0);
    }
  }

  #pragma unroll
  for (int mi = 0; mi < 4; ++mi) {
    const int rbase = wr + mi * 16 + ((lane >> 4) << 2);
    #pragma unroll
    for (int r = 0; r < 4; ++r) {
      const int gm = m0 + rbase + r;
      if (gm >= c) continue;
      const int pair = le[gm];
      unsigned short* dst = h1 + (size_t)pair * H_DIM;
      #pragma unroll
      for (int ni = 0; ni < 4; ++ni) {
        const int col = n0 + wc + ni * 16 + lr;
        const float v = acc[mi][ni][r] + b1[e * H_DIM + col];
        dst[col] = f2bf(fmaxf(v, 0.f));
      }
    }
  }
}

// ---------------- GEMM2: out[tok] += w * (h1_gather @ W2[e] + b2[e]) ----------------
__global__ __launch_bounds__(256, 2) void gemm2_kernel(
    const unsigned short* __restrict__ h1, const float* __restrict__ w2,
    const float* __restrict__ b2, const int* __restrict__ cnt,
    const int* __restrict__ lst, const float* __restrict__ wpair,
    float* __restrict__ out)
{
  const int e = blockIdx.z;
  const int c = cnt[e];
  const int m0 = blockIdx.y * BM;
  if (m0 >= c) return;
  const int n0 = blockIdx.x * BN;
  const float* W = w2 + (size_t)e * H_DIM * H_DIM;
  const int* le = lst + e * T_TOKENS;

  __shared__ unsigned short As[BM * BK];
  __shared__ unsigned short Bs[BN * BK];

  const int tid = threadIdx.x;
  const int lane = tid & 63;
  const int wid = tid >> 6;
  const int wr = (wid >> 1) * 64;
  const int wc = (wid & 1) * 64;
  const int lr = lane & 15;
  const int kh = (lane >> 4) << 3;
  const int sw = (lane & 7) << 3;

  // A staging precompute: 4 x 16B bf16 loads per thread
  const unsigned short* aptr[4];
  int adst[4];
  #pragma unroll
  for (int i = 0; i < 4; ++i) {
    const int idx = i * 256 + tid;
    const int m = idx >> 3;
    const int k8 = (idx & 7) << 3;
    const int gm = m0 + m;
    const int pair = (gm < c) ? le[gm] : le[0];
    aptr[i] = h1 + (size_t)pair * H_DIM + k8;
    adst[i] = m * BK + (k8 ^ ((m & 7) << 3));
  }
  const float* bptr[8];
  int bn4[8], bkr[8];
  #pragma unroll
  for (int i = 0; i < 8; ++i) {
    const int idx = i * 256 + tid;
    const int kr = idx >> 5;
    const int n4 = (idx & 31) << 2;
    bptr[i] = W + (size_t)kr * H_DIM + n0 + n4;
    bn4[i] = n4; bkr[i] = kr;
  }

  f32x4 acc[4][4];
  #pragma unroll
  for (int i = 0; i < 4; ++i)
    #pragma unroll
    for (int j = 0; j < 4; ++j) acc[i][j] = (f32x4){0.f, 0.f, 0.f, 0.f};

  for (int kt = 0; kt < H_DIM; kt += BK) {
    __syncthreads();
    #pragma unroll
    for (int i = 0; i < 4; ++i) {
      const int4 v = *(const int4*)(aptr[i] + kt);
      *(int4*)&As[adst[i]] = v;
    }
    #pragma unroll
    for (int i = 0; i < 8; ++i) {
      const float4 v = *(const float4*)(bptr[i] + (size_t)kt * H_DIM);
      const int n4 = bn4[i], kr = bkr[i];
      Bs[(n4 + 0) * BK + (kr ^ (((n4 + 0) & 7) << 3))] = f2bf(v.x);
      Bs[(n4 + 1) * BK + (kr ^ (((n4 + 1) & 7) << 3))] = f2bf(v.y);
      Bs[(n4 + 2) * BK + (kr ^ (((n4 + 2) & 7) << 3))] = f2bf(v.z);
      Bs[(n4 + 3) * BK + (kr ^ (((n4 + 3) & 7) << 3))] = f2bf(v.w);
    }
    __syncthreads();
    #pragma unroll
    for (int kk = 0; kk < BK; kk += 32) {
      bf16x8 a[4], b[4];
      #pragma unroll
      for (int mi = 0; mi < 4; ++mi) {
        const int row = wr + mi * 16 + lr;
        a[mi] = *reinterpret_cast<const bf16x8*>(&As[row * BK + ((kk + kh) ^ sw)]);
      }
      #pragma unroll
      for (int ni = 0; ni < 4; ++ni) {
        const int row = wc + ni * 16 + lr;
        b[ni] = *reinterpret_cast<const bf16x8*>(&Bs[row * BK + ((kk + kh) ^ sw)]);
      }
      #pragma unroll
      for (int mi = 0; mi < 4; ++mi)
        #pragma unroll
        for (int ni = 0; ni < 4; ++ni)
          acc[mi][ni] = __builtin_amdgcn_mfma_f32_16x16x32_bf16(a[mi], b[ni], acc[mi][ni], 0, 0, 0);
    }
  }

  #pragma unroll
  for (int mi = 0; mi < 4; ++mi) {
    const int rbase = wr + mi * 16 + ((lane >> 4) << 2);
    #pragma unroll
    for (int r = 0; r < 4; ++r) {
      const int gm = m0 + rbase + r;
      if (gm >= c) continue;
      const int pair = le[gm];
      const int tok = pair >> 1;
      const float g = wpair[pair];
      float* dst = out + (size_t)tok * H_DIM;
      #pragma unroll
      for (int ni = 0; ni < 4; ++ni) {
        const int col = n0 + wc + ni * 16 + lr;
        const float v = acc[mi][ni][r] + b2[e * H_DIM + col];
        atomicAdd(&dst[col], g * v);
      }
    }
  }
}

extern "C" void kernel_launch(void* const* d_in, const int* in_sizes, int n_in,
                              void* d_out, int out_size, void* d_ws, size_t ws_size,
                              hipStream_t stream) {
  const float* x      = (const float*)d_in[0];
  const float* gate_w = (const float*)d_in[1];
  const float* gate_b = (const float*)d_in[2];
  const float* w1     = (const float*)d_in[3];
  const float* b1     = (const float*)d_in[4];
  const float* w2     = (const float*)d_in[5];
  const float* b2     = (const float*)d_in[6];

  float* out    = (float*)d_out;
  float* logits = out + (size_t)T_TOKENS * H_DIM;

  char* ws = (char*)d_ws;
  int*   cnt  = (int*)ws;                                   // 32 B
  int*   lst  = (int*)(ws + 256);                           // 8*8192*4 = 256 KB
  float* wpr  = (float*)(ws + 256 + N_EXP * T_TOKENS * 4);  // 64 KB
  unsigned short* h1 = (unsigned short*)(ws + 327936);      // 16384*1024*2 = 32 MB

  hipMemsetAsync(cnt, 0, 32, stream);
  hipMemsetAsync(out, 0, (size_t)T_TOKENS * H_DIM * sizeof(float), stream);

  router_kernel<<<T_TOKENS / 4, 256, 0, stream>>>(x, gate_w, gate_b, logits, cnt, lst, wpr);
  gemm1_kernel<<<dim3(H_DIM / BN, T_TOKENS / BM, N_EXP), 256, 0, stream>>>(x, w1, b1, cnt, lst, h1);
  gemm2_kernel<<<dim3(H_DIM / BN, T_TOKENS / BM, N_EXP), 256, 0, stream>>>(h1, w2, b2, cnt, lst, wpr, out);
}

// Round 2
// 400.853 us; speedup vs baseline: 2.0595x; 2.0595x over previous
//
#include <hip/hip_runtime.h>
#include <hip/hip_bf16.h>

#define T_TOKENS 8192
#define H_DIM    1024
#define N_EXP    8

#define BM 128
#define BN 128
#define BK 64

typedef __attribute__((ext_vector_type(8))) __bf16 bf16x8;
typedef __attribute__((ext_vector_type(4))) float  f32x4;

#define AS1(p) ((const __attribute__((address_space(1))) void*)(p))
#define AS3(p) ((__attribute__((address_space(3))) void*)(p))

__device__ __forceinline__ unsigned short f2bf(float f) {
  unsigned u = __float_as_uint(f);
  u += 0x7fff + ((u >> 16) & 1);   // round-to-nearest-even
  return (unsigned short)(u >> 16);
}

// ---------------- Router: one wave per token (fp32 — selection must match ref) ----------------
__global__ __launch_bounds__(256) void router_kernel(
    const float* __restrict__ x, const float* __restrict__ gw,
    const float* __restrict__ gb, float* __restrict__ logits_out,
    int* __restrict__ cnt, int* __restrict__ lst, float* __restrict__ wpair)
{
  const int tid = threadIdx.x;
  const int lane = tid & 63;
  const int w = tid >> 6;
  const int t = blockIdx.x * 4 + w;
  const float* xr = x + (size_t)t * H_DIM;

  float acc[8];
  #pragma unroll
  for (int e = 0; e < 8; ++e) acc[e] = 0.f;

  #pragma unroll
  for (int i = 0; i < H_DIM / 64; ++i) {
    const int h = i * 64 + lane;
    const float xv = xr[h];
    const float4 g0 = *(const float4*)&gw[h * 8 + 0];
    const float4 g1 = *(const float4*)&gw[h * 8 + 4];
    acc[0] += xv * g0.x; acc[1] += xv * g0.y;
    acc[2] += xv * g0.z; acc[3] += xv * g0.w;
    acc[4] += xv * g1.x; acc[5] += xv * g1.y;
    acc[6] += xv * g1.z; acc[7] += xv * g1.w;
  }
  #pragma unroll
  for (int off = 32; off; off >>= 1) {
    #pragma unroll
    for (int e = 0; e < 8; ++e) acc[e] += __shfl_xor(acc[e], off);
  }
  if (lane == 0) {
    float lg[8];
    #pragma unroll
    for (int e = 0; e < 8; ++e) lg[e] = acc[e] + gb[e];
    #pragma unroll
    for (int e = 0; e < 8; ++e) logits_out[(size_t)t * N_EXP + e] = lg[e];
    int e0 = 0; float v0 = lg[0];
    #pragma unroll
    for (int e = 1; e < 8; ++e) { if (lg[e] > v0) { v0 = lg[e]; e0 = e; } }
    int e1 = -1; float v1 = -3.4e38f;
    #pragma unroll
    for (int e = 0; e < 8; ++e) { if (e != e0 && lg[e] > v1) { v1 = lg[e]; e1 = e; } }
    const float ew = expf(v1 - v0);
    const float r0 = 1.f / (1.f + ew);
    const float r1 = ew / (1.f + ew);
    wpair[2 * t + 0] = r0;
    wpair[2 * t + 1] = r1;
    int p0 = atomicAdd(&cnt[e0], 1); lst[e0 * T_TOKENS + p0] = 2 * t + 0;
    int p1 = atomicAdd(&cnt[e1], 1); lst[e1 * T_TOKENS + p1] = 2 * t + 1;
  }
}

// ---------------- x fp32 -> bf16 ----------------
__global__ __launch_bounds__(256) void xconv_kernel(
    const float* __restrict__ x, unsigned short* __restrict__ xb)
{
  const size_t i = ((size_t)blockIdx.x * 256 + threadIdx.x) * 8;
  const float4 v0 = *(const float4*)&x[i];
  const float4 v1 = *(const float4*)&x[i + 4];
  unsigned short o[8] = {f2bf(v0.x), f2bf(v0.y), f2bf(v0.z), f2bf(v0.w),
                         f2bf(v1.x), f2bf(v1.y), f2bf(v1.z), f2bf(v1.w)};
  *(int4*)&xb[i] = *(int4*)o;
}

// ---------------- W [e][k][n] fp32 -> Wt [e][n][k] bf16 (64x64 LDS-tiled transpose) ----------
__global__ __launch_bounds__(256) void wconv_kernel(
    const float* __restrict__ w, unsigned short* __restrict__ wt)
{
  __shared__ float t[64][65];
  const float* we = w + (size_t)blockIdx.z * H_DIM * H_DIM;
  unsigned short* wte = wt + (size_t)blockIdx.z * H_DIM * H_DIM;
  const int k0 = blockIdx.y * 64, n0 = blockIdx.x * 64;
  const int tid = threadIdx.x;
  #pragma unroll
  for (int r = 0; r < 4; ++r) {
    const int k = (tid >> 4) + r * 16;
    const int n = (tid & 15) * 4;
    const float4 v = *(const float4*)&we[(size_t)(k0 + k) * H_DIM + n0 + n];
    t[n + 0][k] = v.x; t[n + 1][k] = v.y; t[n + 2][k] = v.z; t[n + 3][k] = v.w;
  }
  __syncthreads();
  const int n = tid >> 2, kc = (tid & 3) * 16;
  unsigned short o[16];
  #pragma unroll
  for (int j = 0; j < 16; ++j) o[j] = f2bf(t[n][kc + j]);
  *(int4*)&wte[(size_t)(n0 + n) * H_DIM + k0 + kc] = *(int4*)&o[0];
  *(int4*)&wte[(size_t)(n0 + n) * H_DIM + k0 + kc + 8] = *(int4*)&o[8];
}

// ---------------- GEMM1: h1[pair] = relu(x_gather @ W1[e] + b1[e]) ----------------
// XB=1: A from bf16 xb via global_load_lds. XB=0: A from fp32 x via reg staging.
template<int XB>
__global__ __launch_bounds__(256, 3) void gemm1_kernel(
    const float* __restrict__ x, const unsigned short* __restrict__ xb,
    const unsigned short* __restrict__ w1t, const float* __restrict__ b1,
    const int* __restrict__ cnt, const int* __restrict__ lst,
    unsigned short* __restrict__ h1)
{
  const int e = blockIdx.z;
  const int c = cnt[e];
  const int m0 = blockIdx.y * BM;
  if (m0 >= c) return;
  const int n0 = blockIdx.x * BN;
  const unsigned short* W = w1t + (size_t)e * H_DIM * H_DIM;  // [n][k] bf16
  const int* le = lst + e * T_TOKENS;

  __shared__ unsigned short As[BM * BK];
  __shared__ unsigned short Bs[BN * BK];

  const int tid  = threadIdx.x;
  const int lane = tid & 63;
  const int wid  = tid >> 6;

  // DMA staging geometry: wave w covers rows [32w,32w+32), 4 instrs x 8 rows.
  const int lrow8 = lane >> 3;             // row within 8-row group
  const int csrc  = (lane & 7) ^ lrow8;    // pre-swizzled source chunk (matches read-side XOR)

  const unsigned short* bSrc[4];
  #pragma unroll
  for (int i = 0; i < 4; ++i) {
    const int r = wid * 32 + i * 8 + lrow8;
    bSrc[i] = W + (size_t)(n0 + r) * H_DIM + csrc * 8;
  }

  const unsigned short* aSrcB[4];
  const float* aSrcF[8]; int adst[8];
  if constexpr (XB) {
    #pragma unroll
    for (int i = 0; i < 4; ++i) {
      const int m = wid * 32 + i * 8 + lrow8;
      const int gm = m0 + m;
      const int pair = (gm < c) ? le[gm] : le[0];
      aSrcB[i] = xb + (size_t)(pair >> 1) * H_DIM + csrc * 8;
    }
  } else {
    #pragma unroll
    for (int i = 0; i < 8; ++i) {
      const int idx = i * 256 + tid;
      const int m = idx >> 4;
      const int k4 = (idx & 15) << 2;
      const int gm = m0 + m;
      const int pair = (gm < c) ? le[gm] : le[0];
      aSrcF[i] = x + (size_t)(pair >> 1) * H_DIM + k4;
      adst[i] = m * BK + (k4 ^ ((m & 7) << 3));
    }
  }

  const int wr = (wid >> 1) * 64;
  const int wc = (wid & 1) * 64;
  const int lr = lane & 15;
  const int kh = (lane >> 4) << 3;
  const int sw = (lane & 7) << 3;

  f32x4 acc[4][4];
  #pragma unroll
  for (int i = 0; i < 4; ++i)
    #pragma unroll
    for (int j = 0; j < 4; ++j) acc[i][j] = (f32x4){0.f, 0.f, 0.f, 0.f};

  for (int kt = 0; kt < H_DIM; kt += BK) {
    __syncthreads();
    #pragma unroll
    for (int i = 0; i < 4; ++i)
      __builtin_amdgcn_global_load_lds(AS1(bSrc[i] + kt), AS3(&Bs[(wid * 32 + i * 8) * BK]), 16, 0, 0);
    if constexpr (XB) {
      #pragma unroll
      for (int i = 0; i < 4; ++i)
        __builtin_amdgcn_global_load_lds(AS1(aSrcB[i] + kt), AS3(&As[(wid * 32 + i * 8) * BK]), 16, 0, 0);
    } else {
      #pragma unroll
      for (int i = 0; i < 8; ++i) {
        const float4 v = *(const float4*)(aSrcF[i] + kt);
        short4 s4;
        ((unsigned short*)&s4)[0] = f2bf(v.x);
        ((unsigned short*)&s4)[1] = f2bf(v.y);
        ((unsigned short*)&s4)[2] = f2bf(v.z);
        ((unsigned short*)&s4)[3] = f2bf(v.w);
        *(short4*)&As[adst[i]] = s4;
      }
    }
    __syncthreads();
    #pragma unroll
    for (int kk = 0; kk < BK; kk += 32) {
      bf16x8 a[4], b[4];
      #pragma unroll
      for (int mi = 0; mi < 4; ++mi) {
        const int row = wr + mi * 16 + lr;
        a[mi] = *reinterpret_cast<const bf16x8*>(&As[row * BK + ((kk + kh) ^ sw)]);
      }
      #pragma unroll
      for (int ni = 0; ni < 4; ++ni) {
        const int row = wc + ni * 16 + lr;
        b[ni] = *reinterpret_cast<const bf16x8*>(&Bs[row * BK + ((kk + kh) ^ sw)]);
      }
      #pragma unroll
      for (int mi = 0; mi < 4; ++mi)
        #pragma unroll
        for (int ni = 0; ni < 4; ++ni)
          acc[mi][ni] = __builtin_amdgcn_mfma_f32_16x16x32_bf16(a[mi], b[ni], acc[mi][ni], 0, 0, 0);
    }
  }

  #pragma unroll
  for (int mi = 0; mi < 4; ++mi) {
    const int rbase = wr + mi * 16 + ((lane >> 4) << 2);
    #pragma unroll
    for (int r = 0; r < 4; ++r) {
      const int gm = m0 + rbase + r;
      if (gm >= c) continue;
      const int pair = le[gm];
      unsigned short* dst = h1 + (size_t)pair * H_DIM;
      #pragma unroll
      for (int ni = 0; ni < 4; ++ni) {
        const int col = n0 + wc + ni * 16 + lr;
        const float v = acc[mi][ni][r] + b1[e * H_DIM + col];
        dst[col] = f2bf(fmaxf(v, 0.f));
      }
    }
  }
}

// ---------------- GEMM2: out[tok] += w * (h1_gather @ W2[e] + b2[e]) ----------------
__global__ __launch_bounds__(256, 3) void gemm2_kernel(
    const unsigned short* __restrict__ h1, const unsigned short* __restrict__ w2t,
    const float* __restrict__ b2, const int* __restrict__ cnt,
    const int* __restrict__ lst, const float* __restrict__ wpair,
    float* __restrict__ out)
{
  const int e = blockIdx.z;
  const int c = cnt[e];
  const int m0 = blockIdx.y * BM;
  if (m0 >= c) return;
  const int n0 = blockIdx.x * BN;
  const unsigned short* W = w2t + (size_t)e * H_DIM * H_DIM;
  const int* le = lst + e * T_TOKENS;

  __shared__ unsigned short As[BM * BK];
  __shared__ unsigned short Bs[BN * BK];

  const int tid  = threadIdx.x;
  const int lane = tid & 63;
  const int wid  = tid >> 6;

  const int lrow8 = lane >> 3;
  const int csrc  = (lane & 7) ^ lrow8;

  const unsigned short* aSrc[4];
  const unsigned short* bSrc[4];
  #pragma unroll
  for (int i = 0; i < 4; ++i) {
    const int m = wid * 32 + i * 8 + lrow8;
    const int gm = m0 + m;
    const int pair = (gm < c) ? le[gm] : le[0];
    aSrc[i] = h1 + (size_t)pair * H_DIM + csrc * 8;
    bSrc[i] = W + (size_t)(n0 + m) * H_DIM + csrc * 8;
  }

  const int wr = (wid >> 1) * 64;
  const int wc = (wid & 1) * 64;
  const int lr = lane & 15;
  const int kh = (lane >> 4) << 3;
  const int sw = (lane & 7) << 3;

  f32x4 acc[4][4];
  #pragma unroll
  for (int i = 0; i < 4; ++i)
    #pragma unroll
    for (int j = 0; j < 4; ++j) acc[i][j] = (f32x4){0.f, 0.f, 0.f, 0.f};

  for (int kt = 0; kt < H_DIM; kt += BK) {
    __syncthreads();
    #pragma unroll
    for (int i = 0; i < 4; ++i) {
      __builtin_amdgcn_global_load_lds(AS1(bSrc[i] + kt), AS3(&Bs[(wid * 32 + i * 8) * BK]), 16, 0, 0);
      __builtin_amdgcn_global_load_lds(AS1(aSrc[i] + kt), AS3(&As[(wid * 32 + i * 8) * BK]), 16, 0, 0);
    }
    __syncthreads();
    #pragma unroll
    for (int kk = 0; kk < BK; kk += 32) {
      bf16x8 a[4], b[4];
      #pragma unroll
      for (int mi = 0; mi < 4; ++mi) {
        const int row = wr + mi * 16 + lr;
        a[mi] = *reinterpret_cast<const bf16x8*>(&As[row * BK + ((kk + kh) ^ sw)]);
      }
      #pragma unroll
      for (int ni = 0; ni < 4; ++ni) {
        const int row = wc + ni * 16 + lr;
        b[ni] = *reinterpret_cast<const bf16x8*>(&Bs[row * BK + ((kk + kh) ^ sw)]);
      }
      #pragma unroll
      for (int mi = 0; mi < 4; ++mi)
        #pragma unroll
        for (int ni = 0; ni < 4; ++ni)
          acc[mi][ni] = __builtin_amdgcn_mfma_f32_16x16x32_bf16(a[mi], b[ni], acc[mi][ni], 0, 0, 0);
    }
  }

  #pragma unroll
  for (int mi = 0; mi < 4; ++mi) {
    const int rbase = wr + mi * 16 + ((lane >> 4) << 2);
    #pragma unroll
    for (int r = 0; r < 4; ++r) {
      const int gm = m0 + rbase + r;
      if (gm >= c) continue;
      const int pair = le[gm];
      const int tok = pair >> 1;
      const float g = wpair[pair];
      float* dst = out + (size_t)tok * H_DIM;
      #pragma unroll
      for (int ni = 0; ni < 4; ++ni) {
        const int col = n0 + wc + ni * 16 + lr;
        const float v = acc[mi][ni][r] + b2[e * H_DIM + col];
        atomicAdd(&dst[col], g * v);
      }
    }
  }
}

extern "C" void kernel_launch(void* const* d_in, const int* in_sizes, int n_in,
                              void* d_out, int out_size, void* d_ws, size_t ws_size,
                              hipStream_t stream) {
  const float* x      = (const float*)d_in[0];
  const float* gate_w = (const float*)d_in[1];
  const float* gate_b = (const float*)d_in[2];
  const float* w1     = (const float*)d_in[3];
  const float* b1     = (const float*)d_in[4];
  const float* w2     = (const float*)d_in[5];
  const float* b2     = (const float*)d_in[6];

  float* out    = (float*)d_out;
  float* logits = out + (size_t)T_TOKENS * H_DIM;

  char* ws = (char*)d_ws;
  int*   cnt = (int*)ws;                                     // 32 B (pad 256)
  int*   lst = (int*)(ws + 256);                             // 256 KB
  float* wpr = (float*)(ws + 256 + N_EXP * T_TOKENS * 4);    // 64 KB
  char*  big = ws + 327936;

  const size_t SZ_XB = (size_t)T_TOKENS * H_DIM * 2;          // 16 MB
  const size_t SZ_WT = (size_t)N_EXP * H_DIM * H_DIM * 2;     // 16 MB (reused for w1t then w2t)
  const size_t SZ_H1 = (size_t)2 * T_TOKENS * H_DIM * 2;      // 32 MB
  const bool full = ws_size >= (size_t)327936 + SZ_XB + SZ_WT + SZ_H1;

  unsigned short* xb = (unsigned short*)big;
  unsigned short* wt = (unsigned short*)(big + (full ? SZ_XB : 0));
  unsigned short* h1 = (unsigned short*)(big + (full ? SZ_XB : 0) + SZ_WT);

  hipMemsetAsync(cnt, 0, 32, stream);
  hipMemsetAsync(out, 0, (size_t)T_TOKENS * H_DIM * sizeof(float), stream);

  router_kernel<<<T_TOKENS / 4, 256, 0, stream>>>(x, gate_w, gate_b, logits, cnt, lst, wpr);
  if (full)
    xconv_kernel<<<(T_TOKENS * H_DIM / 8) / 256, 256, 0, stream>>>(x, xb);
  wconv_kernel<<<dim3(16, 16, 8), 256, 0, stream>>>(w1, wt);
  if (full)
    gemm1_kernel<1><<<dim3(H_DIM / BN, T_TOKENS / BM, N_EXP), 256, 0, stream>>>(x, xb, wt, b1, cnt, lst, h1);
  else
    gemm1_kernel<0><<<dim3(H_DIM / BN, T_TOKENS / BM, N_EXP), 256, 0, stream>>>(x, xb, wt, b1, cnt, lst, h1);
  wconv_kernel<<<dim3(16, 16, 8), 256, 0, stream>>>(w2, wt);   // reuse wt (stream-serialized)
  gemm2_kernel<<<dim3(H_DIM / BN, T_TOKENS / BM, N_EXP), 256, 0, stream>>>(h1, wt, b2, cnt, lst, wpr, out);
}

// Round 3
// 223.801 us; speedup vs baseline: 3.6888x; 1.7911x over previous
//
#include <hip/hip_runtime.h>
#include <hip/hip_bf16.h>

#define T_TOKENS 8192
#define H_DIM    1024
#define N_EXP    8

#define BM 128
#define BN 128
#define BK 64

typedef __attribute__((ext_vector_type(8))) __bf16 bf16x8;
typedef __attribute__((ext_vector_type(4))) float  f32x4;

#define AS1(p) ((const __attribute__((address_space(1))) void*)(p))
#define AS3(p) ((__attribute__((address_space(3))) void*)(p))

__device__ __forceinline__ unsigned short f2bf(float f) {
  unsigned u = __float_as_uint(f);
  u += 0x7fff + ((u >> 16) & 1);   // round-to-nearest-even
  return (unsigned short)(u >> 16);
}

// ---------------- Router: one wave per token (fp32 — math identical to validated R1/R2) ------
__global__ __launch_bounds__(256) void router_kernel(
    const float* __restrict__ x, const float* __restrict__ gw,
    const float* __restrict__ gb, float* __restrict__ logits_out,
    int* __restrict__ choice, float* __restrict__ wpair)
{
  const int tid = threadIdx.x;
  const int lane = tid & 63;
  const int w = tid >> 6;
  const int t = blockIdx.x * 4 + w;
  const float* xr = x + (size_t)t * H_DIM;

  float acc[8];
  #pragma unroll
  for (int e = 0; e < 8; ++e) acc[e] = 0.f;

  #pragma unroll
  for (int i = 0; i < H_DIM / 64; ++i) {
    const int h = i * 64 + lane;
    const float xv = xr[h];
    const float4 g0 = *(const float4*)&gw[h * 8 + 0];
    const float4 g1 = *(const float4*)&gw[h * 8 + 4];
    acc[0] += xv * g0.x; acc[1] += xv * g0.y;
    acc[2] += xv * g0.z; acc[3] += xv * g0.w;
    acc[4] += xv * g1.x; acc[5] += xv * g1.y;
    acc[6] += xv * g1.z; acc[7] += xv * g1.w;
  }
  #pragma unroll
  for (int off = 32; off; off >>= 1) {
    #pragma unroll
    for (int e = 0; e < 8; ++e) acc[e] += __shfl_xor(acc[e], off);
  }
  if (lane == 0) {
    float lg[8];
    #pragma unroll
    for (int e = 0; e < 8; ++e) lg[e] = acc[e] + gb[e];
    #pragma unroll
    for (int e = 0; e < 8; ++e) logits_out[(size_t)t * N_EXP + e] = lg[e];
    int e0 = 0; float v0 = lg[0];
    #pragma unroll
    for (int e = 1; e < 8; ++e) { if (lg[e] > v0) { v0 = lg[e]; e0 = e; } }
    int e1 = -1; float v1 = -3.4e38f;
    #pragma unroll
    for (int e = 0; e < 8; ++e) { if (e != e0 && lg[e] > v1) { v1 = lg[e]; e1 = e; } }
    const float ew = expf(v1 - v0);
    const float r0 = 1.f / (1.f + ew);
    const float r1 = ew / (1.f + ew);
    wpair[2 * t + 0] = r0;
    wpair[2 * t + 1] = r1;
    choice[t] = e0 | (e1 << 4);            // no atomics — contention was 195 us
  }
}

// ---------------- Build per-expert pair lists (deterministic, token-ordered) ----------------
__global__ __launch_bounds__(256) void build_lists_kernel(
    const int* __restrict__ choice, int* __restrict__ cnt, int* __restrict__ lst)
{
  const int e = blockIdx.x;
  const int tid = threadIdx.x;
  __shared__ int sc[256];

  const int t0 = tid * 32;
  int ch[32];
  int cl = 0;
  #pragma unroll
  for (int j = 0; j < 32; ++j) {
    ch[j] = choice[t0 + j];
    if ((ch[j] & 15) == e) cl++;
    if ((ch[j] >> 4) == e) cl++;
  }
  sc[tid] = cl;
  __syncthreads();
  #pragma unroll
  for (int off = 1; off < 256; off <<= 1) {
    int u = (tid >= off) ? sc[tid - off] : 0;
    __syncthreads();
    sc[tid] += u;
    __syncthreads();
  }
  int pos = sc[tid] - cl;                  // exclusive base
  int* le = lst + e * T_TOKENS;
  #pragma unroll
  for (int j = 0; j < 32; ++j) {
    if ((ch[j] & 15) == e) le[pos++] = 2 * (t0 + j);
    if ((ch[j] >> 4) == e) le[pos++] = 2 * (t0 + j) + 1;
  }
  if (tid == 255) cnt[e] = sc[255];
}

// ---------------- x fp32 -> bf16 ----------------
__global__ __launch_bounds__(256) void xconv_kernel(
    const float* __restrict__ x, unsigned short* __restrict__ xb)
{
  const size_t i = ((size_t)blockIdx.x * 256 + threadIdx.x) * 8;
  const float4 v0 = *(const float4*)&x[i];
  const float4 v1 = *(const float4*)&x[i + 4];
  unsigned short o[8] = {f2bf(v0.x), f2bf(v0.y), f2bf(v0.z), f2bf(v0.w),
                         f2bf(v1.x), f2bf(v1.y), f2bf(v1.z), f2bf(v1.w)};
  *(int4*)&xb[i] = *(int4*)o;
}

// ---------------- W [e][k][n] fp32 -> Wt [e][n][k] bf16 (64x64 LDS-tiled transpose) ----------
__global__ __launch_bounds__(256) void wconv_kernel(
    const float* __restrict__ w, unsigned short* __restrict__ wt)
{
  __shared__ float t[64][65];
  const float* we = w + (size_t)blockIdx.z * H_DIM * H_DIM;
  unsigned short* wte = wt + (size_t)blockIdx.z * H_DIM * H_DIM;
  const int k0 = blockIdx.y * 64, n0 = blockIdx.x * 64;
  const int tid = threadIdx.x;
  #pragma unroll
  for (int r = 0; r < 4; ++r) {
    const int k = (tid >> 4) + r * 16;
    const int n = (tid & 15) * 4;
    const float4 v = *(const float4*)&we[(size_t)(k0 + k) * H_DIM + n0 + n];
    t[n + 0][k] = v.x; t[n + 1][k] = v.y; t[n + 2][k] = v.z; t[n + 3][k] = v.w;
  }
  __syncthreads();
  const int n = tid >> 2, kc = (tid & 3) * 16;
  unsigned short o[16];
  #pragma unroll
  for (int j = 0; j < 16; ++j) o[j] = f2bf(t[n][kc + j]);
  *(int4*)&wte[(size_t)(n0 + n) * H_DIM + k0 + kc] = *(int4*)&o[0];
  *(int4*)&wte[(size_t)(n0 + n) * H_DIM + k0 + kc + 8] = *(int4*)&o[8];
}

// ---------------- GEMM1: h1[pair] = relu(x_gather @ W1[e] + b1[e]) ----------------
template<int XB>
__global__ __launch_bounds__(256, 3) void gemm1_kernel(
    const float* __restrict__ x, const unsigned short* __restrict__ xb,
    const unsigned short* __restrict__ w1t, const float* __restrict__ b1,
    const int* __restrict__ cnt, const int* __restrict__ lst,
    unsigned short* __restrict__ h1)
{
  const int e = blockIdx.z;
  const int c = cnt[e];
  const int m0 = blockIdx.y * BM;
  if (m0 >= c) return;
  const int n0 = blockIdx.x * BN;
  const unsigned short* W = w1t + (size_t)e * H_DIM * H_DIM;  // [n][k] bf16
  const int* le = lst + e * T_TOKENS;

  __shared__ unsigned short As[BM * BK];
  __shared__ unsigned short Bs[BN * BK];

  const int tid  = threadIdx.x;
  const int lane = tid & 63;
  const int wid  = tid >> 6;

  const int lrow8 = lane >> 3;             // row within 8-row group
  const int csrc  = (lane & 7) ^ lrow8;    // pre-swizzled source chunk (matches read-side XOR)

  const unsigned short* bSrc[4];
  #pragma unroll
  for (int i = 0; i < 4; ++i) {
    const int r = wid * 32 + i * 8 + lrow8;
    bSrc[i] = W + (size_t)(n0 + r) * H_DIM + csrc * 8;
  }

  const unsigned short* aSrcB[4];
  const float* aSrcF[8]; int adst[8];
  if constexpr (XB) {
    #pragma unroll
    for (int i = 0; i < 4; ++i) {
      const int m = wid * 32 + i * 8 + lrow8;
      const int gm = m0 + m;
      const int pair = (gm < c) ? le[gm] : le[0];
      aSrcB[i] = xb + (size_t)(pair >> 1) * H_DIM + csrc * 8;
    }
  } else {
    #pragma unroll
    for (int i = 0; i < 8; ++i) {
      const int idx = i * 256 + tid;
      const int m = idx >> 4;
      const int k4 = (idx & 15) << 2;
      const int gm = m0 + m;
      const int pair = (gm < c) ? le[gm] : le[0];
      aSrcF[i] = x + (size_t)(pair >> 1) * H_DIM + k4;
      adst[i] = m * BK + (k4 ^ ((m & 7) << 3));
    }
  }

  const int wr = (wid >> 1) * 64;
  const int wc = (wid & 1) * 64;
  const int lr = lane & 15;
  const int kh = (lane >> 4) << 3;
  const int sw = (lane & 7) << 3;

  f32x4 acc[4][4];
  #pragma unroll
  for (int i = 0; i < 4; ++i)
    #pragma unroll
    for (int j = 0; j < 4; ++j) acc[i][j] = (f32x4){0.f, 0.f, 0.f, 0.f};

  for (int kt = 0; kt < H_DIM; kt += BK) {
    __syncthreads();
    #pragma unroll
    for (int i = 0; i < 4; ++i)
      __builtin_amdgcn_global_load_lds(AS1(bSrc[i] + kt), AS3(&Bs[(wid * 32 + i * 8) * BK]), 16, 0, 0);
    if constexpr (XB) {
      #pragma unroll
      for (int i = 0; i < 4; ++i)
        __builtin_amdgcn_global_load_lds(AS1(aSrcB[i] + kt), AS3(&As[(wid * 32 + i * 8) * BK]), 16, 0, 0);
    } else {
      #pragma unroll
      for (int i = 0; i < 8; ++i) {
        const float4 v = *(const float4*)(aSrcF[i] + kt);
        short4 s4;
        ((unsigned short*)&s4)[0] = f2bf(v.x);
        ((unsigned short*)&s4)[1] = f2bf(v.y);
        ((unsigned short*)&s4)[2] = f2bf(v.z);
        ((unsigned short*)&s4)[3] = f2bf(v.w);
        *(short4*)&As[adst[i]] = s4;
      }
    }
    __syncthreads();
    #pragma unroll
    for (int kk = 0; kk < BK; kk += 32) {
      bf16x8 a[4], b[4];
      #pragma unroll
      for (int mi = 0; mi < 4; ++mi) {
        const int row = wr + mi * 16 + lr;
        a[mi] = *reinterpret_cast<const bf16x8*>(&As[row * BK + ((kk + kh) ^ sw)]);
      }
      #pragma unroll
      for (int ni = 0; ni < 4; ++ni) {
        const int row = wc + ni * 16 + lr;
        b[ni] = *reinterpret_cast<const bf16x8*>(&Bs[row * BK + ((kk + kh) ^ sw)]);
      }
      #pragma unroll
      for (int mi = 0; mi < 4; ++mi)
        #pragma unroll
        for (int ni = 0; ni < 4; ++ni)
          acc[mi][ni] = __builtin_amdgcn_mfma_f32_16x16x32_bf16(a[mi], b[ni], acc[mi][ni], 0, 0, 0);
    }
  }

  #pragma unroll
  for (int mi = 0; mi < 4; ++mi) {
    const int rbase = wr + mi * 16 + ((lane >> 4) << 2);
    #pragma unroll
    for (int r = 0; r < 4; ++r) {
      const int gm = m0 + rbase + r;
      if (gm >= c) continue;
      const int pair = le[gm];
      unsigned short* dst = h1 + (size_t)pair * H_DIM;
      #pragma unroll
      for (int ni = 0; ni < 4; ++ni) {
        const int col = n0 + wc + ni * 16 + lr;
        const float v = acc[mi][ni][r] + b1[e * H_DIM + col];
        dst[col] = f2bf(fmaxf(v, 0.f));
      }
    }
  }
}

// ---------------- GEMM2: out[tok] += w * (h1_gather @ W2[e] + b2[e]) ----------------
__global__ __launch_bounds__(256, 3) void gemm2_kernel(
    const unsigned short* __restrict__ h1, const unsigned short* __restrict__ w2t,
    const float* __restrict__ b2, const int* __restrict__ cnt,
    const int* __restrict__ lst, const float* __restrict__ wpair,
    float* __restrict__ out)
{
  const int e = blockIdx.z;
  const int c = cnt[e];
  const int m0 = blockIdx.y * BM;
  if (m0 >= c) return;
  const int n0 = blockIdx.x * BN;
  const unsigned short* W = w2t + (size_t)e * H_DIM * H_DIM;
  const int* le = lst + e * T_TOKENS;

  __shared__ unsigned short As[BM * BK];
  __shared__ unsigned short Bs[BN * BK];

  const int tid  = threadIdx.x;
  const int lane = tid & 63;
  const int wid  = tid >> 6;

  const int lrow8 = lane >> 3;
  const int csrc  = (lane & 7) ^ lrow8;

  const unsigned short* aSrc[4];
  const unsigned short* bSrc[4];
  #pragma unroll
  for (int i = 0; i < 4; ++i) {
    const int m = wid * 32 + i * 8 + lrow8;
    const int gm = m0 + m;
    const int pair = (gm < c) ? le[gm] : le[0];
    aSrc[i] = h1 + (size_t)pair * H_DIM + csrc * 8;
    bSrc[i] = W + (size_t)(n0 + m) * H_DIM + csrc * 8;
  }

  const int wr = (wid >> 1) * 64;
  const int wc = (wid & 1) * 64;
  const int lr = lane & 15;
  const int kh = (lane >> 4) << 3;
  const int sw = (lane & 7) << 3;

  f32x4 acc[4][4];
  #pragma unroll
  for (int i = 0; i < 4; ++i)
    #pragma unroll
    for (int j = 0; j < 4; ++j) acc[i][j] = (f32x4){0.f, 0.f, 0.f, 0.f};

  for (int kt = 0; kt < H_DIM; kt += BK) {
    __syncthreads();
    #pragma unroll
    for (int i = 0; i < 4; ++i) {
      __builtin_amdgcn_global_load_lds(AS1(bSrc[i] + kt), AS3(&Bs[(wid * 32 + i * 8) * BK]), 16, 0, 0);
      __builtin_amdgcn_global_load_lds(AS1(aSrc[i] + kt), AS3(&As[(wid * 32 + i * 8) * BK]), 16, 0, 0);
    }
    __syncthreads();
    #pragma unroll
    for (int kk = 0; kk < BK; kk += 32) {
      bf16x8 a[4], b[4];
      #pragma unroll
      for (int mi = 0; mi < 4; ++mi) {
        const int row = wr + mi * 16 + lr;
        a[mi] = *reinterpret_cast<const bf16x8*>(&As[row * BK + ((kk + kh) ^ sw)]);
      }
      #pragma unroll
      for (int ni = 0; ni < 4; ++ni) {
        const int row = wc + ni * 16 + lr;
        b[ni] = *reinterpret_cast<const bf16x8*>(&Bs[row * BK + ((kk + kh) ^ sw)]);
      }
      #pragma unroll
      for (int mi = 0; mi < 4; ++mi)
        #pragma unroll
        for (int ni = 0; ni < 4; ++ni)
          acc[mi][ni] = __builtin_amdgcn_mfma_f32_16x16x32_bf16(a[mi], b[ni], acc[mi][ni], 0, 0, 0);
    }
  }

  #pragma unroll
  for (int mi = 0; mi < 4; ++mi) {
    const int rbase = wr + mi * 16 + ((lane >> 4) << 2);
    #pragma unroll
    for (int r = 0; r < 4; ++r) {
      const int gm = m0 + rbase + r;
      if (gm >= c) continue;
      const int pair = le[gm];
      const int tok = pair >> 1;
      const float g = wpair[pair];
      float* dst = out + (size_t)tok * H_DIM;
      #pragma unroll
      for (int ni = 0; ni < 4; ++ni) {
        const int col = n0 + wc + ni * 16 + lr;
        const float v = acc[mi][ni][r] + b2[e * H_DIM + col];
        atomicAdd(&dst[col], g * v);
      }
    }
  }
}

extern "C" void kernel_launch(void* const* d_in, const int* in_sizes, int n_in,
                              void* d_out, int out_size, void* d_ws, size_t ws_size,
                              hipStream_t stream) {
  const float* x      = (const float*)d_in[0];
  const float* gate_w = (const float*)d_in[1];
  const float* gate_b = (const float*)d_in[2];
  const float* w1     = (const float*)d_in[3];
  const float* b1     = (const float*)d_in[4];
  const float* w2     = (const float*)d_in[5];
  const float* b2     = (const float*)d_in[6];

  float* out    = (float*)d_out;
  float* logits = out + (size_t)T_TOKENS * H_DIM;

  char* ws = (char*)d_ws;
  int*   cnt    = (int*)ws;                                      // 32 B (pad 256)
  int*   lst    = (int*)(ws + 256);                              // 256 KB
  float* wpr    = (float*)(ws + 256 + N_EXP * T_TOKENS * 4);     // 64 KB
  int*   choice = (int*)(ws + 327936);                           // 32 KB
  char*  big    = ws + 327936 + 32768;

  const size_t SZ_XB = (size_t)T_TOKENS * H_DIM * 2;          // 16 MB
  const size_t SZ_WT = (size_t)N_EXP * H_DIM * H_DIM * 2;     // 16 MB (reused for w1t then w2t)
  const size_t SZ_H1 = (size_t)2 * T_TOKENS * H_DIM * 2;      // 32 MB
  const bool full = ws_size >= (size_t)(327936 + 32768) + SZ_XB + SZ_WT + SZ_H1;

  unsigned short* xb = (unsigned short*)big;
  unsigned short* wt = (unsigned short*)(big + (full ? SZ_XB : 0));
  unsigned short* h1 = (unsigned short*)(big + (full ? SZ_XB : 0) + SZ_WT);

  hipMemsetAsync(out, 0, (size_t)T_TOKENS * H_DIM * sizeof(float), stream);

  router_kernel<<<T_TOKENS / 4, 256, 0, stream>>>(x, gate_w, gate_b, logits, choice, wpr);
  build_lists_kernel<<<N_EXP, 256, 0, stream>>>(choice, cnt, lst);
  if (full)
    xconv_kernel<<<(T_TOKENS * H_DIM / 8) / 256, 256, 0, stream>>>(x, xb);
  wconv_kernel<<<dim3(16, 16, 8), 256, 0, stream>>>(w1, wt);
  if (full)
    gemm1_kernel<1><<<dim3(H_DIM / BN, T_TOKENS / BM, N_EXP), 256, 0, stream>>>(x, xb, wt, b1, cnt, lst, h1);
  else
    gemm1_kernel<0><<<dim3(H_DIM / BN, T_TOKENS / BM, N_EXP), 256, 0, stream>>>(x, xb, wt, b1, cnt, lst, h1);
  wconv_kernel<<<dim3(16, 16, 8), 256, 0, stream>>>(w2, wt);   // reuse wt (stream-serialized)
  gemm2_kernel<<<dim3(H_DIM / BN, T_TOKENS / BM, N_EXP), 256, 0, stream>>>(h1, wt, b2, cnt, lst, wpr, out);
}

// Round 4
// 163.901 us; speedup vs baseline: 5.0369x; 1.3655x over previous
//
#include <hip/hip_runtime.h>
#include <hip/hip_bf16.h>

#define T_TOKENS 8192
#define H_DIM    1024
#define N_EXP    8

#define BM 128
#define BN 128
#define BK 64

typedef __attribute__((ext_vector_type(8))) __bf16 bf16x8;
typedef __attribute__((ext_vector_type(4))) float  f32x4;

#define AS1(p) ((const __attribute__((address_space(1))) void*)(p))
#define AS3(p) ((__attribute__((address_space(3))) void*)(p))

__device__ __forceinline__ unsigned short f2bf(float f) {
  unsigned u = __float_as_uint(f);
  u += 0x7fff + ((u >> 16) & 1);   // round-to-nearest-even
  return (unsigned short)(u >> 16);
}
__device__ __forceinline__ float bf2f(unsigned short s) {
  return __uint_as_float(((unsigned)s) << 16);
}

// XCD-locality block swizzle: id%8 == m%8 so one (m,e)-panel's 8 n-blocks run on
// one XCD (A-panel 256KB + expert's 8 B-panels 2MB stay L2-resident; L2=4MB/XCD).
__device__ __forceinline__ void decode_blk(int id, int& e, int& m0, int& n0) {
  const int xg = id & 7;
  const int g  = id >> 3;
  const int nblk = g & 7;
  const int mblk = ((g >> 3) & 7) * 8 + xg;
  e  = g >> 6;
  m0 = mblk * BM;
  n0 = nblk * BN;
}

// ---------------- Router: one wave per token (fp32 math identical to validated R1-R3) -------
// Also emits xb (bf16 copy of x) when xb != nullptr — fuses xconv's extra 32MB read away.
__global__ __launch_bounds__(256) void router_kernel(
    const float* __restrict__ x, const float* __restrict__ gw,
    const float* __restrict__ gb, float* __restrict__ logits_out,
    int* __restrict__ choice, float* __restrict__ wpair,
    unsigned short* __restrict__ xb)
{
  const int tid = threadIdx.x;
  const int lane = tid & 63;
  const int w = tid >> 6;
  const int t = blockIdx.x * 4 + w;
  const float* xr = x + (size_t)t * H_DIM;

  float acc[8];
  #pragma unroll
  for (int e = 0; e < 8; ++e) acc[e] = 0.f;

  #pragma unroll
  for (int i = 0; i < H_DIM / 64; ++i) {
    const int h = i * 64 + lane;
    const float xv = xr[h];
    if (xb) xb[(size_t)t * H_DIM + h] = f2bf(xv);
    const float4 g0 = *(const float4*)&gw[h * 8 + 0];
    const float4 g1 = *(const float4*)&gw[h * 8 + 4];
    acc[0] += xv * g0.x; acc[1] += xv * g0.y;
    acc[2] += xv * g0.z; acc[3] += xv * g0.w;
    acc[4] += xv * g1.x; acc[5] += xv * g1.y;
    acc[6] += xv * g1.z; acc[7] += xv * g1.w;
  }
  #pragma unroll
  for (int off = 32; off; off >>= 1) {
    #pragma unroll
    for (int e = 0; e < 8; ++e) acc[e] += __shfl_xor(acc[e], off);
  }
  if (lane == 0) {
    float lg[8];
    #pragma unroll
    for (int e = 0; e < 8; ++e) lg[e] = acc[e] + gb[e];
    #pragma unroll
    for (int e = 0; e < 8; ++e) logits_out[(size_t)t * N_EXP + e] = lg[e];
    int e0 = 0; float v0 = lg[0];
    #pragma unroll
    for (int e = 1; e < 8; ++e) { if (lg[e] > v0) { v0 = lg[e]; e0 = e; } }
    int e1 = -1; float v1 = -3.4e38f;
    #pragma unroll
    for (int e = 0; e < 8; ++e) { if (e != e0 && lg[e] > v1) { v1 = lg[e]; e1 = e; } }
    const float ew = expf(v1 - v0);
    const float r0 = 1.f / (1.f + ew);
    const float r1 = ew / (1.f + ew);
    wpair[2 * t + 0] = r0;
    wpair[2 * t + 1] = r1;
    choice[t] = e0 | (e1 << 4);
  }
}

// ---------------- Build per-expert pair lists (deterministic, token-ordered) ----------------
__global__ __launch_bounds__(256) void build_lists_kernel(
    const int* __restrict__ choice, int* __restrict__ cnt, int* __restrict__ lst)
{
  const int e = blockIdx.x;
  const int tid = threadIdx.x;
  __shared__ int sc[256];

  const int t0 = tid * 32;
  int ch[32];
  int cl = 0;
  #pragma unroll
  for (int j = 0; j < 32; ++j) {
    ch[j] = choice[t0 + j];
    if ((ch[j] & 15) == e) cl++;
    if ((ch[j] >> 4) == e) cl++;
  }
  sc[tid] = cl;
  __syncthreads();
  #pragma unroll
  for (int off = 1; off < 256; off <<= 1) {
    int u = (tid >= off) ? sc[tid - off] : 0;
    __syncthreads();
    sc[tid] += u;
    __syncthreads();
  }
  int pos = sc[tid] - cl;
  int* le = lst + e * T_TOKENS;
  #pragma unroll
  for (int j = 0; j < 32; ++j) {
    if ((ch[j] & 15) == e) le[pos++] = 2 * (t0 + j);
    if ((ch[j] >> 4) == e) le[pos++] = 2 * (t0 + j) + 1;
  }
  if (tid == 255) cnt[e] = sc[255];
}

// ---------------- W [e][k][n] fp32 -> Wt [e][n][k] bf16 (64x64 LDS-tiled transpose) ----------
__global__ __launch_bounds__(256) void wconv_kernel(
    const float* __restrict__ w, unsigned short* __restrict__ wt)
{
  __shared__ float t[64][65];
  const float* we = w + (size_t)blockIdx.z * H_DIM * H_DIM;
  unsigned short* wte = wt + (size_t)blockIdx.z * H_DIM * H_DIM;
  const int k0 = blockIdx.y * 64, n0 = blockIdx.x * 64;
  const int tid = threadIdx.x;
  #pragma unroll
  for (int r = 0; r < 4; ++r) {
    const int k = (tid >> 4) + r * 16;
    const int n = (tid & 15) * 4;
    const float4 v = *(const float4*)&we[(size_t)(k0 + k) * H_DIM + n0 + n];
    t[n + 0][k] = v.x; t[n + 1][k] = v.y; t[n + 2][k] = v.z; t[n + 3][k] = v.w;
  }
  __syncthreads();
  const int n = tid >> 2, kc = (tid & 3) * 16;
  unsigned short o[16];
  #pragma unroll
  for (int j = 0; j < 16; ++j) o[j] = f2bf(t[n][kc + j]);
  *(int4*)&wte[(size_t)(n0 + n) * H_DIM + k0 + kc] = *(int4*)&o[0];
  *(int4*)&wte[(size_t)(n0 + n) * H_DIM + k0 + kc + 8] = *(int4*)&o[8];
}

// ---------------- GEMM1: h1[pair] = wpair[pair] * relu(x_gather @ W1[e] + b1[e]) ------------
template<int XB>
__global__ __launch_bounds__(256, 3) void gemm1_kernel(
    const float* __restrict__ x, const unsigned short* __restrict__ xb,
    const unsigned short* __restrict__ w1t, const float* __restrict__ b1,
    const int* __restrict__ cnt, const int* __restrict__ lst,
    const float* __restrict__ wpair, unsigned short* __restrict__ h1)
{
  int e, m0, n0;
  decode_blk(blockIdx.x, e, m0, n0);
  const int c = cnt[e];
  if (m0 >= c) return;
  const unsigned short* W = w1t + (size_t)e * H_DIM * H_DIM;  // [n][k] bf16
  const int* le = lst + e * T_TOKENS;

  __shared__ unsigned short As[BM * BK];
  __shared__ unsigned short Bs[BN * BK];

  const int tid  = threadIdx.x;
  const int lane = tid & 63;
  const int wid  = tid >> 6;

  const int lrow8 = lane >> 3;             // row within 8-row group
  const int csrc  = (lane & 7) ^ lrow8;    // pre-swizzled source chunk (matches read-side XOR)

  const unsigned short* bSrc[4];
  #pragma unroll
  for (int i = 0; i < 4; ++i) {
    const int r = wid * 32 + i * 8 + lrow8;
    bSrc[i] = W + (size_t)(n0 + r) * H_DIM + csrc * 8;
  }

  const unsigned short* aSrcB[4];
  const float* aSrcF[8]; int adst[8];
  if constexpr (XB) {
    #pragma unroll
    for (int i = 0; i < 4; ++i) {
      const int m = wid * 32 + i * 8 + lrow8;
      const int gm = m0 + m;
      const int pair = (gm < c) ? le[gm] : le[0];
      aSrcB[i] = xb + (size_t)(pair >> 1) * H_DIM + csrc * 8;
    }
  } else {
    #pragma unroll
    for (int i = 0; i < 8; ++i) {
      const int idx = i * 256 + tid;
      const int m = idx >> 4;
      const int k4 = (idx & 15) << 2;
      const int gm = m0 + m;
      const int pair = (gm < c) ? le[gm] : le[0];
      aSrcF[i] = x + (size_t)(pair >> 1) * H_DIM + k4;
      adst[i] = m * BK + (k4 ^ ((m & 7) << 3));
    }
  }

  const int wr = (wid >> 1) * 64;
  const int wc = (wid & 1) * 64;
  const int lr = lane & 15;
  const int kh = (lane >> 4) << 3;
  const int sw = (lane & 7) << 3;

  f32x4 acc[4][4];
  #pragma unroll
  for (int i = 0; i < 4; ++i)
    #pragma unroll
    for (int j = 0; j < 4; ++j) acc[i][j] = (f32x4){0.f, 0.f, 0.f, 0.f};

  for (int kt = 0; kt < H_DIM; kt += BK) {
    __syncthreads();
    #pragma unroll
    for (int i = 0; i < 4; ++i)
      __builtin_amdgcn_global_load_lds(AS1(bSrc[i] + kt), AS3(&Bs[(wid * 32 + i * 8) * BK]), 16, 0, 0);
    if constexpr (XB) {
      #pragma unroll
      for (int i = 0; i < 4; ++i)
        __builtin_amdgcn_global_load_lds(AS1(aSrcB[i] + kt), AS3(&As[(wid * 32 + i * 8) * BK]), 16, 0, 0);
    } else {
      #pragma unroll
      for (int i = 0; i < 8; ++i) {
        const float4 v = *(const float4*)(aSrcF[i] + kt);
        short4 s4;
        ((unsigned short*)&s4)[0] = f2bf(v.x);
        ((unsigned short*)&s4)[1] = f2bf(v.y);
        ((unsigned short*)&s4)[2] = f2bf(v.z);
        ((unsigned short*)&s4)[3] = f2bf(v.w);
        *(short4*)&As[adst[i]] = s4;
      }
    }
    __syncthreads();
    #pragma unroll
    for (int kk = 0; kk < BK; kk += 32) {
      bf16x8 a[4], b[4];
      #pragma unroll
      for (int mi = 0; mi < 4; ++mi) {
        const int row = wr + mi * 16 + lr;
        a[mi] = *reinterpret_cast<const bf16x8*>(&As[row * BK + ((kk + kh) ^ sw)]);
      }
      #pragma unroll
      for (int ni = 0; ni < 4; ++ni) {
        const int row = wc + ni * 16 + lr;
        b[ni] = *reinterpret_cast<const bf16x8*>(&Bs[row * BK + ((kk + kh) ^ sw)]);
      }
      #pragma unroll
      for (int mi = 0; mi < 4; ++mi)
        #pragma unroll
        for (int ni = 0; ni < 4; ++ni)
          acc[mi][ni] = __builtin_amdgcn_mfma_f32_16x16x32_bf16(a[mi], b[ni], acc[mi][ni], 0, 0, 0);
    }
  }

  #pragma unroll
  for (int mi = 0; mi < 4; ++mi) {
    const int rbase = wr + mi * 16 + ((lane >> 4) << 2);
    #pragma unroll
    for (int r = 0; r < 4; ++r) {
      const int gm = m0 + rbase + r;
      if (gm >= c) continue;
      const int pair = le[gm];
      const float g = wpair[pair];          // fold router weight into h1 (g > 0)
      unsigned short* dst = h1 + (size_t)pair * H_DIM;
      #pragma unroll
      for (int ni = 0; ni < 4; ++ni) {
        const int col = n0 + wc + ni * 16 + lr;
        const float v = acc[mi][ni][r] + b1[e * H_DIM + col];
        dst[col] = f2bf(g * fmaxf(v, 0.f));
      }
    }
  }
}

// ---------------- GEMM2: OE=1: oe[pair] = (g*h1) @ W2[e]  (bf16 plain stores) ----------------
//                  OE=0: out[tok] += (g*h1)@W2 + g*b2  (atomic fallback)
template<int OE>
__global__ __launch_bounds__(256, 3) void gemm2_kernel(
    const unsigned short* __restrict__ h1, const unsigned short* __restrict__ w2t,
    const float* __restrict__ b2, const int* __restrict__ cnt,
    const int* __restrict__ lst, const float* __restrict__ wpair,
    unsigned short* __restrict__ oe, float* __restrict__ out)
{
  int e, m0, n0;
  decode_blk(blockIdx.x, e, m0, n0);
  const int c = cnt[e];
  if (m0 >= c) return;
  const unsigned short* W = w2t + (size_t)e * H_DIM * H_DIM;
  const int* le = lst + e * T_TOKENS;

  __shared__ unsigned short As[BM * BK];
  __shared__ unsigned short Bs[BN * BK];

  const int tid  = threadIdx.x;
  const int lane = tid & 63;
  const int wid  = tid >> 6;

  const int lrow8 = lane >> 3;
  const int csrc  = (lane & 7) ^ lrow8;

  const unsigned short* aSrc[4];
  const unsigned short* bSrc[4];
  #pragma unroll
  for (int i = 0; i < 4; ++i) {
    const int m = wid * 32 + i * 8 + lrow8;
    const int gm = m0 + m;
    const int pair = (gm < c) ? le[gm] : le[0];
    aSrc[i] = h1 + (size_t)pair * H_DIM + csrc * 8;
    bSrc[i] = W + (size_t)(n0 + m) * H_DIM + csrc * 8;
  }

  const int wr = (wid >> 1) * 64;
  const int wc = (wid & 1) * 64;
  const int lr = lane & 15;
  const int kh = (lane >> 4) << 3;
  const int sw = (lane & 7) << 3;

  f32x4 acc[4][4];
  #pragma unroll
  for (int i = 0; i < 4; ++i)
    #pragma unroll
    for (int j = 0; j < 4; ++j) acc[i][j] = (f32x4){0.f, 0.f, 0.f, 0.f};

  for (int kt = 0; kt < H_DIM; kt += BK) {
    __syncthreads();
    #pragma unroll
    for (int i = 0; i < 4; ++i) {
      __builtin_amdgcn_global_load_lds(AS1(bSrc[i] + kt), AS3(&Bs[(wid * 32 + i * 8) * BK]), 16, 0, 0);
      __builtin_amdgcn_global_load_lds(AS1(aSrc[i] + kt), AS3(&As[(wid * 32 + i * 8) * BK]), 16, 0, 0);
    }
    __syncthreads();
    #pragma unroll
    for (int kk = 0; kk < BK; kk += 32) {
      bf16x8 a[4], b[4];
      #pragma unroll
      for (int mi = 0; mi < 4; ++mi) {
        const int row = wr + mi * 16 + lr;
        a[mi] = *reinterpret_cast<const bf16x8*>(&As[row * BK + ((kk + kh) ^ sw)]);
      }
      #pragma unroll
      for (int ni = 0; ni < 4; ++ni) {
        const int row = wc + ni * 16 + lr;
        b[ni] = *reinterpret_cast<const bf16x8*>(&Bs[row * BK + ((kk + kh) ^ sw)]);
      }
      #pragma unroll
      for (int mi = 0; mi < 4; ++mi)
        #pragma unroll
        for (int ni = 0; ni < 4; ++ni)
          acc[mi][ni] = __builtin_amdgcn_mfma_f32_16x16x32_bf16(a[mi], b[ni], acc[mi][ni], 0, 0, 0);
    }
  }

  #pragma unroll
  for (int mi = 0; mi < 4; ++mi) {
    const int rbase = wr + mi * 16 + ((lane >> 4) << 2);
    #pragma unroll
    for (int r = 0; r < 4; ++r) {
      const int gm = m0 + rbase + r;
      if (gm >= c) continue;
      const int pair = le[gm];
      if constexpr (OE) {
        unsigned short* dst = oe + (size_t)pair * H_DIM;
        #pragma unroll
        for (int ni = 0; ni < 4; ++ni) {
          const int col = n0 + wc + ni * 16 + lr;
          dst[col] = f2bf(acc[mi][ni][r]);
        }
      } else {
        const int tok = pair >> 1;
        const float g = wpair[pair];
        float* dst = out + (size_t)tok * H_DIM;
        #pragma unroll
        for (int ni = 0; ni < 4; ++ni) {
          const int col = n0 + wc + ni * 16 + lr;
          atomicAdd(&dst[col], acc[mi][ni][r] + g * b2[e * H_DIM + col]);
        }
      }
    }
  }
}

// ---------------- Combine: out[t] = oe[2t] + oe[2t+1] + g0*b2[e0] + g1*b2[e1] ----------------
__global__ __launch_bounds__(256) void combine_kernel(
    const unsigned short* __restrict__ oe, const int* __restrict__ choice,
    const float* __restrict__ wpair, const float* __restrict__ b2,
    float* __restrict__ out)
{
  const int tid = threadIdx.x;
  const int t = blockIdx.x * 2 + (tid >> 7);
  const int col = (tid & 127) * 8;
  const int ch = choice[t];
  const int e0 = ch & 15, e1 = ch >> 4;
  const float g0 = wpair[2 * t], g1 = wpair[2 * t + 1];

  const unsigned short* o0 = oe + (size_t)(2 * t) * H_DIM + col;
  const unsigned short* o1 = oe + (size_t)(2 * t + 1) * H_DIM + col;
  int4 a = *(const int4*)o0;
  int4 b = *(const int4*)o1;
  const unsigned short* pa = (const unsigned short*)&a;
  const unsigned short* pb = (const unsigned short*)&b;
  const float* b2r0 = b2 + e0 * H_DIM + col;
  const float* b2r1 = b2 + e1 * H_DIM + col;
  float4 c0 = *(const float4*)&b2r0[0];
  float4 c1 = *(const float4*)&b2r0[4];
  float4 d0 = *(const float4*)&b2r1[0];
  float4 d1 = *(const float4*)&b2r1[4];
  float r[8];
  r[0] = bf2f(pa[0]) + bf2f(pb[0]) + g0 * c0.x + g1 * d0.x;
  r[1] = bf2f(pa[1]) + bf2f(pb[1]) + g0 * c0.y + g1 * d0.y;
  r[2] = bf2f(pa[2]) + bf2f(pb[2]) + g0 * c0.z + g1 * d0.z;
  r[3] = bf2f(pa[3]) + bf2f(pb[3]) + g0 * c0.w + g1 * d0.w;
  r[4] = bf2f(pa[4]) + bf2f(pb[4]) + g0 * c1.x + g1 * d1.x;
  r[5] = bf2f(pa[5]) + bf2f(pb[5]) + g0 * c1.y + g1 * d1.y;
  r[6] = bf2f(pa[6]) + bf2f(pb[6]) + g0 * c1.z + g1 * d1.z;
  r[7] = bf2f(pa[7]) + bf2f(pb[7]) + g0 * c1.w + g1 * d1.w;
  float* dst = out + (size_t)t * H_DIM + col;
  *(float4*)&dst[0] = *(float4*)&r[0];
  *(float4*)&dst[4] = *(float4*)&r[4];
}

extern "C" void kernel_launch(void* const* d_in, const int* in_sizes, int n_in,
                              void* d_out, int out_size, void* d_ws, size_t ws_size,
                              hipStream_t stream) {
  const float* x      = (const float*)d_in[0];
  const float* gate_w = (const float*)d_in[1];
  const float* gate_b = (const float*)d_in[2];
  const float* w1     = (const float*)d_in[3];
  const float* b1     = (const float*)d_in[4];
  const float* w2     = (const float*)d_in[5];
  const float* b2     = (const float*)d_in[6];

  float* out    = (float*)d_out;
  float* logits = out + (size_t)T_TOKENS * H_DIM;

  char* ws = (char*)d_ws;
  int*   cnt    = (int*)ws;                                        // 256 B
  int*   lst    = (int*)(ws + 256);                                // 256 KB
  float* wpr    = (float*)(ws + 256 + N_EXP * T_TOKENS * 4);       // 64 KB
  int*   choice = (int*)(ws + 256 + N_EXP * T_TOKENS * 4 + 2 * T_TOKENS * 4);  // 32 KB
  char*  big    = ws + 360704;

  const size_t SZ_XB = (size_t)T_TOKENS * H_DIM * 2;          // 16 MB
  const size_t SZ_WT = (size_t)N_EXP * H_DIM * H_DIM * 2;     // 16 MB (reused for w1t then w2t)
  const size_t SZ_H1 = (size_t)2 * T_TOKENS * H_DIM * 2;      // 32 MB
  const size_t SZ_OE = (size_t)2 * T_TOKENS * H_DIM * 2;      // 32 MB
  const bool full = ws_size >= (size_t)360704 + SZ_XB + SZ_WT + SZ_H1 + SZ_OE;

  unsigned short* xb = (unsigned short*)big;
  unsigned short* wt = (unsigned short*)(big + (full ? SZ_XB : 0));
  unsigned short* h1 = (unsigned short*)(big + (full ? SZ_XB : 0) + SZ_WT);
  unsigned short* oe = (unsigned short*)(big + SZ_XB + SZ_WT + SZ_H1);

  const int GEMM_GRID = (H_DIM / BN) * (T_TOKENS / BM) * N_EXP;   // 4096

  if (full) {
    router_kernel<<<T_TOKENS / 4, 256, 0, stream>>>(x, gate_w, gate_b, logits, choice, wpr, xb);
    build_lists_kernel<<<N_EXP, 256, 0, stream>>>(choice, cnt, lst);
    wconv_kernel<<<dim3(16, 16, 8), 256, 0, stream>>>(w1, wt);
    gemm1_kernel<1><<<GEMM_GRID, 256, 0, stream>>>(x, xb, wt, b1, cnt, lst, wpr, h1);
    wconv_kernel<<<dim3(16, 16, 8), 256, 0, stream>>>(w2, wt);   // reuse wt (stream-serialized)
    gemm2_kernel<1><<<GEMM_GRID, 256, 0, stream>>>(h1, wt, b2, cnt, lst, wpr, oe, out);
    combine_kernel<<<T_TOKENS / 2, 256, 0, stream>>>(oe, choice, wpr, b2, out);
  } else {
    hipMemsetAsync(out, 0, (size_t)T_TOKENS * H_DIM * sizeof(float), stream);
    router_kernel<<<T_TOKENS / 4, 256, 0, stream>>>(x, gate_w, gate_b, logits, choice, wpr, nullptr);
    build_lists_kernel<<<N_EXP, 256, 0, stream>>>(choice, cnt, lst);
    wconv_kernel<<<dim3(16, 16, 8), 256, 0, stream>>>(w1, wt);
    gemm1_kernel<0><<<GEMM_GRID, 256, 0, stream>>>(x, xb, wt, b1, cnt, lst, wpr, h1);
    wconv_kernel<<<dim3(16, 16, 8), 256, 0, stream>>>(w2, wt);
    gemm2_kernel<0><<<GEMM_GRID, 256, 0, stream>>>(h1, wt, b2, cnt, lst, wpr, oe, out);
  }
}